// Round 8
// baseline (112.540 us; speedup 1.0000x reference)
//
#include <hip/hip_runtime.h>
#include <hip/hip_bf16.h>
#include <math.h>

// LOGG3D_ATTN, MFMA flash-attention v8.
//   topK==1 -> top_k is a permutation -> SOP permutation-invariant -> skipped.
//   /k and L2-norm cancel -> M = sum w_i^2 f_i f_i^T, normalized.
//   exp never overflows (s/4 <= ~14) -> no online max; partials linear in j.
// v8: NO LDS in attn. ghi/gFt are 384 KB each = L2-resident (Common-mistake
//   #7: staging L2-fit data is pure overhead). Reading operands straight from
//   global deletes the stage loops and BOTH barriers -> no convoy stalls,
//   VGPR down -> 6 blocks/CU x 4 waves co-resident. Per-wave aS read is one
//   coalesced 512B segment; aV is 16x32B L2-hit segments; all 4 waves of a
//   block read the same aS/aV -> L1 serves repeats.
//   (v7's 2-stage pipeline was neutral -> reverted; pack_rhu/perm kept.)

#define NP 12288
#define JSPLIT 16
#define JCHUNK (NP / JSPLIT)   // 768
#define JGTOT (JCHUNK / 16)    // 48

// 0.25 * log2(e)
#define QSCALE 0.3606737602222839f

typedef __attribute__((ext_vector_type(4))) float f32x4;
typedef __attribute__((ext_vector_type(2))) unsigned u32x2;
typedef __attribute__((ext_vector_type(8))) short s16x8;
typedef __attribute__((ext_vector_type(4))) short s16x4;

#if defined(__has_builtin)
#if __has_builtin(__builtin_amdgcn_mfma_f32_16x16x16bf16_1k)
#define HAVE_MFMA16_BUILTIN 1
#endif
#if __has_builtin(__builtin_amdgcn_exp2f)
#define EXP2F(x) __builtin_amdgcn_exp2f(x)
#endif
#if __has_builtin(__builtin_amdgcn_perm)
#define HAVE_PERM 1
#endif
#endif
#ifndef EXP2F
#define EXP2F(x) exp2f(x)
#endif

static __device__ __forceinline__ f32x4 mfma16(s16x4 a, s16x4 b, f32x4 c) {
#ifdef HAVE_MFMA16_BUILTIN
    return __builtin_amdgcn_mfma_f32_16x16x16bf16_1k(a, b, c, 0, 0, 0);
#else
    f32x4 d;
    asm volatile("s_nop 1\n\t"
                 "v_mfma_f32_16x16x16_bf16 %0, %1, %2, %0"
                 : "=v"(d)
                 : "v"(a), "v"(b), "0"(c));
    return d;
#endif
}

static __device__ __forceinline__ short f2bf(float x) {
    __hip_bfloat16 h = __float2bfloat16(x);
    return __builtin_bit_cast(short, h);
}

// 4x f32 -> 4x bf16, round-half-up: (bits + 0x8000) >> 16, pair-packed.
static __device__ __forceinline__ s16x4 pack_rhu(f32x4 e) {
    const unsigned u0 = __builtin_bit_cast(unsigned, e[0]) + 0x8000u;
    const unsigned u1 = __builtin_bit_cast(unsigned, e[1]) + 0x8000u;
    const unsigned u2 = __builtin_bit_cast(unsigned, e[2]) + 0x8000u;
    const unsigned u3 = __builtin_bit_cast(unsigned, e[3]) + 0x8000u;
    u32x2 t;
#ifdef HAVE_PERM
    t[0] = __builtin_amdgcn_perm(u1, u0, 0x07060302u);
    t[1] = __builtin_amdgcn_perm(u3, u2, 0x07060302u);
#else
    t[0] = (u0 >> 16) | (u1 & 0xFFFF0000u);
    t[1] = (u2 >> 16) | (u3 & 0xFFFF0000u);
#endif
    return __builtin_bit_cast(s16x4, t);
}

static __device__ __forceinline__ f32x4 exp4(f32x4 s) {
    f32x4 e;
    e[0] = EXP2F(s[0]); e[1] = EXP2F(s[1]);
    e[2] = EXP2F(s[2]); e[3] = EXP2F(s[3]);
    return e;
}

// ---------------- prep: fp32 feats -> bf16 operands ----------------
//  ghi[N][16] = bf16(f)            (j-side score operand)
//  shi[N][16] = bf16(f * QSCALE)   (i-side, 1/sqrt(D) and log2e folded)
//  gFt[16][N] = bf16(f) transposed (V^T planes), via LDS transpose.
__global__ __launch_bounds__(256)
void prep(const float* __restrict__ feats,
          unsigned short* __restrict__ ghi, unsigned short* __restrict__ shi,
          unsigned short* __restrict__ gFt)
{
    __shared__ unsigned short tr[64 * 16];       // 2 KB
    const int tid = threadIdx.x;
    const int rowbase = blockIdx.x * 64;         // 192 blocks x 64 rows

    const f32x4 v = *(const f32x4*)(feats + (size_t)rowbase * 16 + tid * 4);
    s16x4 hv, sv;
    #pragma unroll
    for (int k = 0; k < 4; ++k) {
        hv[k] = f2bf(v[k]);
        sv[k] = f2bf(v[k] * QSCALE);
    }
    *(s16x4*)(ghi + (size_t)rowbase * 16 + tid * 4) = hv;
    *(s16x4*)(shi + (size_t)rowbase * 16 + tid * 4) = sv;
    *(s16x4*)(tr + (tid >> 2) * 16 + (tid & 3) * 4) = hv;
    __syncthreads();

    if (tid < 128) {
        const int p = tid >> 3, q8 = tid & 7;    // plane, 8-row group
        s16x8 o;
        #pragma unroll
        for (int e = 0; e < 8; ++e) o[e] = (short)tr[(q8 * 8 + e) * 16 + p];
        *(s16x8*)(gFt + (size_t)p * NP + rowbase + q8 * 8) = o;
    }
}

// ------------- kernel 1: MFMA flash attention partials (no LDS) -------------
__global__ __launch_bounds__(256)
void attn_mfma(const unsigned short* __restrict__ ghi,
               const unsigned short* __restrict__ shi,
               const unsigned short* __restrict__ gFt,
               float* __restrict__ ctx_part,   // [JSPLIT][N][16]
               float* __restrict__ l_part)     // [JSPLIT][N]
{
    const int tid = threadIdx.x;
    const int wave = tid >> 6, lane = tid & 63;
    const int il = lane & 15, g = lane >> 4, g4 = g * 4, g8 = g * 8;
    const int js = blockIdx.x & (JSPLIT - 1);
    const int rowblk = blockIdx.x >> 4;              // 0..95
    const int ibase = rowblk * 128 + wave * 32;      // wave owns 32 i-rows
    const int jbase = js * JCHUNK;

    // i-side B fragments (prescaled), constant over the loop
    const s16x4 bA = *(const s16x4*)(shi + (size_t)(ibase + il) * 16 + g4);
    const s16x4 bB = *(const s16x4*)(shi + (size_t)(ibase + 16 + il) * 16 + g4);

    s16x4 ones; ones[0] = ones[1] = ones[2] = ones[3] = (short)0x3F80;
    const f32x4 kZero = {0.f, 0.f, 0.f, 0.f};
    f32x4 ctxA = kZero, ctxB = kZero, lA = kZero, lB = kZero;

    // per-lane global read bases (all L2-resident)
    //  aS: row jbase+jg*16+il, shorts g4..g4+3  (wave = one 512B segment)
    //  aV: plane il, cols jbase+jg*16+g4..+3    (16x 32B segments, L1-shared)
    const char* pS = (const char*)ghi + (size_t)(jbase + il) * 32 + g8;
    const char* pV = (const char*)gFt + (size_t)il * (NP * 2)
                     + (size_t)jbase * 2 + g8;

    #pragma unroll 4
    for (int jg = 0; jg < JGTOT; ++jg) {
        const s16x4 aS = *(const s16x4*)(pS + (size_t)jg * 512);
        const s16x4 aV = *(const s16x4*)(pV + (size_t)jg * 32);
        const f32x4 sa = mfma16(aS, bA, kZero);   // S^T * log2e/4
        const f32x4 sb = mfma16(aS, bB, kZero);
        const s16x4 pA = pack_rhu(exp4(sa));
        const s16x4 pB = pack_rhu(exp4(sb));
        ctxA = mfma16(aV, pA, ctxA);              // ctx^T partial
        lA   = mfma16(ones, pA, lA);              // row-sum l (same P bits)
        ctxB = mfma16(aV, pB, ctxB);
        lB   = mfma16(ones, pB, lB);
    }

    asm volatile("s_nop 7\n\ts_nop 7" ::: );      // asm-fallback hazard guard

    const int iA = ibase + il, iB = iA + 16;
    *(f32x4*)(ctx_part + ((size_t)js * NP + iA) * 16 + g4) = ctxA;
    *(f32x4*)(ctx_part + ((size_t)js * NP + iB) * 16 + g4) = ctxB;
    if (g == 0) {
        l_part[(size_t)js * NP + iA] = lA[0];
        l_part[(size_t)js * NP + iB] = lB[0];
    }
}

// -------- kernel 2: combine partials -> weights -> per-block SOP partial -----
__global__ __launch_bounds__(256)
void weights_sop(const float* __restrict__ feats,
                 const float* __restrict__ ctxp,
                 const float* __restrict__ lp,
                 float* __restrict__ mpart)     // [192][256]
{
    __shared__ float gw[64 * 16];
    const int tid = threadIdx.x;
    const int rl = tid >> 2, q = tid & 3, d0 = q * 4;
    const int row = blockIdx.x * 64 + rl;

    f32x4 c = {0.f, 0.f, 0.f, 0.f};
    float l = 0.f;
    #pragma unroll
    for (int js = 0; js < JSPLIT; ++js) {
        c += *(const f32x4*)(ctxp + ((size_t)js * NP + row) * 16 + d0);
        l += lp[(size_t)js * NP + row];
    }
    const f32x4 fv = *(const f32x4*)(feats + (size_t)row * 16 + d0);
    float zp = c[0]*fv[0] + c[1]*fv[1] + c[2]*fv[2] + c[3]*fv[3];
    zp += __shfl_xor(zp, 1, 64);
    zp += __shfl_xor(zp, 2, 64);
    const float z = zp / l;
    const float w = 1.f / (1.f + EXP2F(-z * 1.4426950408889634f));

    f32x4 gv; gv[0] = w*fv[0]; gv[1] = w*fv[1]; gv[2] = w*fv[2]; gv[3] = w*fv[3];
    *(f32x4*)(gw + rl * 16 + d0) = gv;
    __syncthreads();

    const int d = tid >> 4, e = tid & 15;
    float acc = 0.f;
    #pragma unroll 8
    for (int r = 0; r < 64; ++r)
        acc += gw[r * 16 + d] * gw[r * 16 + e];
    mpart[(size_t)blockIdx.x * 256 + tid] = acc;
}

// ---------------- kernel 3: reduce + L2 normalize (1024 threads) -------------
__global__ __launch_bounds__(1024)
void finalize(const float* __restrict__ mpart, float* __restrict__ out)
{
    __shared__ float part[1024];
    __shared__ float red[4];
    const int tid = threadIdx.x;
    const int o = tid & 255, s = tid >> 8;       // output elem, slice 0..3

    float m = 0.f;
    #pragma unroll 4
    for (int b = s; b < 192; b += 4) m += mpart[(size_t)b * 256 + o];
    part[tid] = m;
    __syncthreads();

    if (tid < 256) {
        m = part[tid] + part[tid + 256] + part[tid + 512] + part[tid + 768];
        float ss = m * m;
        #pragma unroll
        for (int msk = 32; msk >= 1; msk >>= 1) ss += __shfl_xor(ss, msk, 64);
        if ((tid & 63) == 0) red[tid >> 6] = ss;
    }
    __syncthreads();
    if (tid < 256) {
        const float tot = red[0] + red[1] + red[2] + red[3];
        out[tid] = m / sqrtf(tot);
    }
}

extern "C" void kernel_launch(void* const* d_in, const int* in_sizes, int n_in,
                              void* d_out, int out_size, void* d_ws, size_t ws_size,
                              hipStream_t stream) {
    (void)n_in; (void)out_size; (void)ws_size;
    const float* feats = (const float*)d_in[0];
    // d_in[1] (topK==1): k==N -> top-k is a no-op for the SOP.

    char* w = (char*)d_ws;
    unsigned short* ghi = (unsigned short*)(w);                  //   393216 B
    unsigned short* shi = (unsigned short*)(w + 393216);         //   393216 B
    unsigned short* gFt = (unsigned short*)(w + 786432);         //   393216 B
    float* ctxp = (float*)(w + 1179648);                         // 12582912 B
    float* lp   = (float*)(w + 13762560);                        //   786432 B
    float* mp   = (float*)(w + 14548992);                        //   196608 B
    // total 14745600 B

    prep       <<<192,  256, 0, stream>>>(feats, ghi, shi, gFt);
    attn_mfma  <<<1536, 256, 0, stream>>>(ghi, shi, gFt, ctxp, lp);
    weights_sop<<<192,  256, 0, stream>>>(feats, ctxp, lp, mp);
    finalize   <<<1,    1024, 0, stream>>>(mp, (float*)d_out);
}

// Round 9
// 94.568 us; speedup vs baseline: 1.1900x; 1.1900x over previous
//
#include <hip/hip_runtime.h>
#include <hip/hip_bf16.h>
#include <math.h>

// LOGG3D_ATTN, MFMA flash-attention v9.
//   topK==1 -> top_k is a permutation -> SOP permutation-invariant -> skipped.
//   /k and L2-norm cancel -> M = sum w_i^2 f_i f_i^T, normalized.
//   exp never overflows (s/4 <= ~14) -> no online max; partials linear in j.
// v9 post-mortem-driven (v8: global-direct was LATENCY-bound, VALU 22%/Mfma
// 21%/Occ 55% -> both pipes idle; LDS restored):
//   - 64 i-rows per wave (4 B-frags, 4 ctx/l accs): one aS+aV LDS read feeds
//     12 MFMAs (was 6) -> jg instances and LDS reads halve.
//   - JSPLIT=32, NTILES=1 (JT=JCHUNK=384): ONE stage + ONE barrier pair per
//     block (v7 had 2 tiles x 2 syncs). Grid stays 48x32=1536.
//   - staging + XOR swizzles byte-identical to v7 (proven correct).

#define NP 12288
#define JSPLIT 32
#define JCHUNK (NP / JSPLIT)   // 384
#define JT JCHUNK              // single tile
#define JGPT (JT / 16)         // 24

// 0.25 * log2(e)
#define QSCALE 0.3606737602222839f

typedef __attribute__((ext_vector_type(4))) float f32x4;
typedef __attribute__((ext_vector_type(2))) unsigned u32x2;
typedef __attribute__((ext_vector_type(8))) short s16x8;
typedef __attribute__((ext_vector_type(4))) short s16x4;

#if defined(__has_builtin)
#if __has_builtin(__builtin_amdgcn_mfma_f32_16x16x16bf16_1k)
#define HAVE_MFMA16_BUILTIN 1
#endif
#if __has_builtin(__builtin_amdgcn_exp2f)
#define EXP2F(x) __builtin_amdgcn_exp2f(x)
#endif
#if __has_builtin(__builtin_amdgcn_perm)
#define HAVE_PERM 1
#endif
#endif
#ifndef EXP2F
#define EXP2F(x) exp2f(x)
#endif

static __device__ __forceinline__ f32x4 mfma16(s16x4 a, s16x4 b, f32x4 c) {
#ifdef HAVE_MFMA16_BUILTIN
    return __builtin_amdgcn_mfma_f32_16x16x16bf16_1k(a, b, c, 0, 0, 0);
#else
    f32x4 d;
    asm volatile("s_nop 1\n\t"
                 "v_mfma_f32_16x16x16_bf16 %0, %1, %2, %0"
                 : "=v"(d)
                 : "v"(a), "v"(b), "0"(c));
    return d;
#endif
}

static __device__ __forceinline__ short f2bf(float x) {
    __hip_bfloat16 h = __float2bfloat16(x);
    return __builtin_bit_cast(short, h);
}

// 4x f32 -> 4x bf16, round-half-up: (bits + 0x8000) >> 16, pair-packed.
static __device__ __forceinline__ s16x4 pack_rhu(f32x4 e) {
    const unsigned u0 = __builtin_bit_cast(unsigned, e[0]) + 0x8000u;
    const unsigned u1 = __builtin_bit_cast(unsigned, e[1]) + 0x8000u;
    const unsigned u2 = __builtin_bit_cast(unsigned, e[2]) + 0x8000u;
    const unsigned u3 = __builtin_bit_cast(unsigned, e[3]) + 0x8000u;
    u32x2 t;
#ifdef HAVE_PERM
    t[0] = __builtin_amdgcn_perm(u1, u0, 0x07060302u);
    t[1] = __builtin_amdgcn_perm(u3, u2, 0x07060302u);
#else
    t[0] = (u0 >> 16) | (u1 & 0xFFFF0000u);
    t[1] = (u2 >> 16) | (u3 & 0xFFFF0000u);
#endif
    return __builtin_bit_cast(s16x4, t);
}

static __device__ __forceinline__ f32x4 exp4(f32x4 s) {
    f32x4 e;
    e[0] = EXP2F(s[0]); e[1] = EXP2F(s[1]);
    e[2] = EXP2F(s[2]); e[3] = EXP2F(s[3]);
    return e;
}

// ---------------- prep: fp32 feats -> bf16 operands ----------------
//  ghi[N][16] = bf16(f)            (j-side score operand)
//  shi[N][16] = bf16(f * QSCALE)   (i-side, 1/sqrt(D) and log2e folded)
//  gFt[16][N] = bf16(f) transposed (V^T planes), via LDS transpose.
__global__ __launch_bounds__(256)
void prep(const float* __restrict__ feats,
          unsigned short* __restrict__ ghi, unsigned short* __restrict__ shi,
          unsigned short* __restrict__ gFt)
{
    __shared__ unsigned short tr[64 * 16];       // 2 KB
    const int tid = threadIdx.x;
    const int rowbase = blockIdx.x * 64;         // 192 blocks x 64 rows

    const f32x4 v = *(const f32x4*)(feats + (size_t)rowbase * 16 + tid * 4);
    s16x4 hv, sv;
    #pragma unroll
    for (int k = 0; k < 4; ++k) {
        hv[k] = f2bf(v[k]);
        sv[k] = f2bf(v[k] * QSCALE);
    }
    *(s16x4*)(ghi + (size_t)rowbase * 16 + tid * 4) = hv;
    *(s16x4*)(shi + (size_t)rowbase * 16 + tid * 4) = sv;
    *(s16x4*)(tr + (tid >> 2) * 16 + (tid & 3) * 4) = hv;
    __syncthreads();

    if (tid < 128) {
        const int p = tid >> 3, q8 = tid & 7;    // plane, 8-row group
        s16x8 o;
        #pragma unroll
        for (int e = 0; e < 8; ++e) o[e] = (short)tr[(q8 * 8 + e) * 16 + p];
        *(s16x8*)(gFt + (size_t)p * NP + rowbase + q8 * 8) = o;
    }
}

// ---------------- kernel 1: MFMA flash attention partials ----------------
__global__ __launch_bounds__(256)
void attn_mfma(const unsigned short* __restrict__ ghi,
               const unsigned short* __restrict__ shi,
               const unsigned short* __restrict__ gFt,
               float* __restrict__ ctx_part,   // [JSPLIT][N][16]
               float* __restrict__ l_part)     // [JSPLIT][N]
{
    __shared__ unsigned short hiT[JT * 16];   // 12 KB, row-XOR-swizzled
    __shared__ unsigned short FtT[16 * JT];   // 12 KB, plane-XOR-swizzled

    const int tid = threadIdx.x;
    const int wave = tid >> 6, lane = tid & 63;
    const int il = lane & 15, g = lane >> 4, g4 = g * 4, g8 = g * 8;
    const int js = blockIdx.x & (JSPLIT - 1);
    const int rowblk = blockIdx.x >> 5;              // 0..47
    const int ibase = rowblk * 256 + wave * 64;      // wave owns 64 i-rows
    const int jbase = js * JCHUNK;

    // 4 i-side B fragments (prescaled), constant over the loop
    s16x4 bF[4];
    #pragma unroll
    for (int t = 0; t < 4; ++t)
        bF[t] = *(const s16x4*)(shi + (size_t)(ibase + t * 16 + il) * 16 + g4);

    s16x4 ones; ones[0] = ones[1] = ones[2] = ones[3] = (short)0x3F80;
    const f32x4 kZero = {0.f, 0.f, 0.f, 0.f};
    f32x4 ctx[4], lacc[4];
    #pragma unroll
    for (int t = 0; t < 4; ++t) { ctx[t] = kZero; lacc[t] = kZero; }

    const char* aBase = (const char*)hiT + ((il * 32 + g8) ^ ((il & 7) << 4));
    const char* vPlane = (const char*)FtT + il * (JT * 2);
    const int vKey = (il & 7) << 4;

    const int fp = tid >> 4, fq = tid & 15;          // Ft staging: plane, chunk

    // ---- stage the single j-tile: hi rows + V^T planes (swizzle at write) ---
    {
        const char* gH = (const char*)ghi + (size_t)jbase * 32;
        #pragma unroll
        for (int k = 0; k < 3; ++k) {                // 768 chunks of 16B
            const int c = tid + (k << 8);
            s16x8 v = *(const s16x8*)(gH + c * 16);
            *(s16x8*)((char*)hiT + ((c * 16) ^ (((c >> 1) & 7) << 4))) = v;
        }
        const char* gF = (const char*)gFt + (size_t)fp * (NP * 2) + (size_t)jbase * 2;
        #pragma unroll
        for (int k = 0; k < 3; ++k) {                // 48 chunks per plane
            const int cq = fq + (k << 4);
            s16x8 v = *(const s16x8*)(gF + cq * 16);
            *(s16x8*)((char*)FtT + fp * (JT * 2)
                      + ((cq * 16) ^ ((fp & 7) << 4))) = v;
        }
    }
    __syncthreads();

    #pragma unroll 2
    for (int jg = 0; jg < JGPT; ++jg) {
        const s16x4 aS = *(const s16x4*)(aBase + jg * 512);
        const s16x4 aV = *(const s16x4*)(vPlane + (((jg << 5) + g8) ^ vKey));
        #pragma unroll
        for (int t = 0; t < 4; ++t) {
            const f32x4 s = mfma16(aS, bF[t], kZero);   // S^T * log2e/4
            const s16x4 p = pack_rhu(exp4(s));
            ctx[t]  = mfma16(aV, p, ctx[t]);            // ctx^T partial
            lacc[t] = mfma16(ones, p, lacc[t]);         // row-sum l
        }
    }

    asm volatile("s_nop 7\n\ts_nop 7" ::: );

    #pragma unroll
    for (int t = 0; t < 4; ++t) {
        const int iT = ibase + t * 16 + il;
        *(f32x4*)(ctx_part + ((size_t)js * NP + iT) * 16 + g4) = ctx[t];
        if (g == 0) l_part[(size_t)js * NP + iT] = lacc[t][0];
    }
}

// -------- kernel 2: combine partials -> weights -> per-block SOP partial -----
__global__ __launch_bounds__(256)
void weights_sop(const float* __restrict__ feats,
                 const float* __restrict__ ctxp,
                 const float* __restrict__ lp,
                 float* __restrict__ mpart)     // [192][256]
{
    __shared__ float gw[64 * 16];
    const int tid = threadIdx.x;
    const int rl = tid >> 2, q = tid & 3, d0 = q * 4;
    const int row = blockIdx.x * 64 + rl;

    f32x4 c = {0.f, 0.f, 0.f, 0.f};
    float l = 0.f;
    #pragma unroll 8
    for (int js = 0; js < JSPLIT; ++js) {
        c += *(const f32x4*)(ctxp + ((size_t)js * NP + row) * 16 + d0);
        l += lp[(size_t)js * NP + row];
    }
    const f32x4 fv = *(const f32x4*)(feats + (size_t)row * 16 + d0);
    float zp = c[0]*fv[0] + c[1]*fv[1] + c[2]*fv[2] + c[3]*fv[3];
    zp += __shfl_xor(zp, 1, 64);
    zp += __shfl_xor(zp, 2, 64);
    const float z = zp / l;
    const float w = 1.f / (1.f + EXP2F(-z * 1.4426950408889634f));

    f32x4 gv; gv[0] = w*fv[0]; gv[1] = w*fv[1]; gv[2] = w*fv[2]; gv[3] = w*fv[3];
    *(f32x4*)(gw + rl * 16 + d0) = gv;
    __syncthreads();

    const int d = tid >> 4, e = tid & 15;
    float acc = 0.f;
    #pragma unroll 8
    for (int r = 0; r < 64; ++r)
        acc += gw[r * 16 + d] * gw[r * 16 + e];
    mpart[(size_t)blockIdx.x * 256 + tid] = acc;
}

// ---------------- kernel 3: reduce + L2 normalize (1024 threads) -------------
__global__ __launch_bounds__(1024)
void finalize(const float* __restrict__ mpart, float* __restrict__ out)
{
    __shared__ float part[1024];
    __shared__ float red[4];
    const int tid = threadIdx.x;
    const int o = tid & 255, s = tid >> 8;       // output elem, slice 0..3

    float m = 0.f;
    #pragma unroll 4
    for (int b = s; b < 192; b += 4) m += mpart[(size_t)b * 256 + o];
    part[tid] = m;
    __syncthreads();

    if (tid < 256) {
        m = part[tid] + part[tid + 256] + part[tid + 512] + part[tid + 768];
        float ss = m * m;
        #pragma unroll
        for (int msk = 32; msk >= 1; msk >>= 1) ss += __shfl_xor(ss, msk, 64);
        if ((tid & 63) == 0) red[tid >> 6] = ss;
    }
    __syncthreads();
    if (tid < 256) {
        const float tot = red[0] + red[1] + red[2] + red[3];
        out[tid] = m / sqrtf(tot);
    }
}

extern "C" void kernel_launch(void* const* d_in, const int* in_sizes, int n_in,
                              void* d_out, int out_size, void* d_ws, size_t ws_size,
                              hipStream_t stream) {
    (void)n_in; (void)out_size; (void)ws_size;
    const float* feats = (const float*)d_in[0];
    // d_in[1] (topK==1): k==N -> top-k is a no-op for the SOP.

    char* w = (char*)d_ws;
    unsigned short* ghi = (unsigned short*)(w);                  //   393216 B
    unsigned short* shi = (unsigned short*)(w + 393216);         //   393216 B
    unsigned short* gFt = (unsigned short*)(w + 786432);         //   393216 B
    float* ctxp = (float*)(w + 1179648);                         // 25165824 B
    float* lp   = (float*)(w + 26345472);                        //  1572864 B
    float* mp   = (float*)(w + 27918336);                        //   196608 B
    // total 28114944 B

    prep       <<<192,  256, 0, stream>>>(feats, ghi, shi, gFt);
    attn_mfma  <<<1536, 256, 0, stream>>>(ghi, shi, gFt, ctxp, lp);
    weights_sop<<<192,  256, 0, stream>>>(feats, ctxp, lp, mp);
    finalize   <<<1,    1024, 0, stream>>>(mp, (float*)d_out);
}